// Round 2
// baseline (12289.937 us; speedup 1.0000x reference)
//
#include <hip/hip_runtime.h>

#define BATCH 64
#define SEQ   512
#define INP   512
#define HID   1024
#define MAGIC 0x13570000u

// ============================================================================
// Phase 1: out[m][n] = sum_f X[m][f] * Wih[n][f] + bih[n] + bhh[n]
// Classic fp32 SGEMM: 128x128 tile, BK=8, 256 threads, 8x8 micro (split +0/+64)
// ~130 us (1.5% of baseline) — unchanged this round.
// ============================================================================
__global__ __launch_bounds__(256) void xw_gemm(
    const float* __restrict__ X, const float* __restrict__ Wih,
    const float* __restrict__ bih, const float* __restrict__ bhh,
    float* __restrict__ out)
{
    __shared__ float As[8][128];
    __shared__ float Bs[8][128];
    const int t  = threadIdx.x;
    const int m0 = blockIdx.x * 128;
    const int n0 = blockIdx.y * 128;
    const int lr = t >> 1;
    const int lk = (t & 1) * 4;
    const int ty = t >> 4;
    const int tx = t & 15;

    float acc[8][8];
#pragma unroll
    for (int i = 0; i < 8; ++i)
#pragma unroll
        for (int j = 0; j < 8; ++j) acc[i][j] = 0.f;

    const float* xrow = X   + (size_t)(m0 + lr) * INP + lk;
    const float* wrow = Wih + (size_t)(n0 + lr) * INP + lk;

    for (int k0 = 0; k0 < INP; k0 += 8) {
        float4 av = *(const float4*)(xrow + k0);
        float4 bv = *(const float4*)(wrow + k0);
        __syncthreads();
        As[lk + 0][lr] = av.x; As[lk + 1][lr] = av.y;
        As[lk + 2][lr] = av.z; As[lk + 3][lr] = av.w;
        Bs[lk + 0][lr] = bv.x; Bs[lk + 1][lr] = bv.y;
        Bs[lk + 2][lr] = bv.z; Bs[lk + 3][lr] = bv.w;
        __syncthreads();
#pragma unroll
        for (int kk = 0; kk < 8; ++kk) {
            float4 a0 = *(const float4*)&As[kk][ty * 4];
            float4 a1 = *(const float4*)&As[kk][64 + ty * 4];
            float4 b0 = *(const float4*)&Bs[kk][tx * 4];
            float4 b1 = *(const float4*)&Bs[kk][64 + tx * 4];
            float am[8] = {a0.x, a0.y, a0.z, a0.w, a1.x, a1.y, a1.z, a1.w};
            float bn[8] = {b0.x, b0.y, b0.z, b0.w, b1.x, b1.y, b1.z, b1.w};
#pragma unroll
            for (int i = 0; i < 8; ++i)
#pragma unroll
                for (int j = 0; j < 8; ++j)
                    acc[i][j] = fmaf(am[i], bn[j], acc[i][j]);
        }
    }

    const int nA = n0 + tx * 4;
    const int nB = n0 + 64 + tx * 4;
    float4 bA1 = *(const float4*)(bih + nA);
    float4 bA2 = *(const float4*)(bhh + nA);
    float4 bB1 = *(const float4*)(bih + nB);
    float4 bB2 = *(const float4*)(bhh + nB);
    float4 biasA = make_float4(bA1.x + bA2.x, bA1.y + bA2.y, bA1.z + bA2.z, bA1.w + bA2.w);
    float4 biasB = make_float4(bB1.x + bB2.x, bB1.y + bB2.y, bB1.z + bB2.z, bB1.w + bB2.w);

#pragma unroll
    for (int i = 0; i < 8; ++i) {
        int mloc = (i < 4) ? (ty * 4 + i) : (64 + ty * 4 + (i - 4));
        size_t m = (size_t)(m0 + mloc);
        float4 vA = make_float4(acc[i][0] + biasA.x, acc[i][1] + biasA.y,
                                acc[i][2] + biasA.z, acc[i][3] + biasA.w);
        float4 vB = make_float4(acc[i][4] + biasB.x, acc[i][5] + biasB.y,
                                acc[i][6] + biasB.z, acc[i][7] + biasB.w);
        *(float4*)(out + m * HID + nA) = vA;
        *(float4*)(out + m * HID + nB) = vB;
    }
}

// ============================================================================
// Phase 2: persistent sequential scan, in-place on out.
// R2: 512-thread blocks (8 waves = 2/SIMD), kc-split x8, explicit double-
// buffered h prefetch, xw prefetch hoisted above the flag poll.
// Grid/flag protocol identical to R1: 256 blocks = 4 groups(16b) x 64 jtiles.
// Wave wv: batch-quad wb=wv>>1, j-octet wj=wv&1. Lane: kc=lane>>3, jl=lane&7.
// Each ds_read_b128 of W feeds 16 fma (4 batches x 4 k) — keeps LDS off the
// critical path (~256 b128/CU/step ~ 2.5k cyc vs 2048 cyc fma issue).
// ============================================================================
__global__ __launch_bounds__(512, 2) void rnn_scan(
    const float* __restrict__ Whh, float* __restrict__ out,
    unsigned* __restrict__ flags)
{
    __shared__ float4 Wlds[16][256];   // 64 KB; row r, logical col c at (c+r)&255

    const int t  = threadIdx.x;
    const int g  = blockIdx.x >> 6;    // batch group 0..3 (16 batches)
    const int jt = blockIdx.x & 63;    // j tile 0..63 (16 j)

    // ---- stage W tile rows jt*16 .. jt*16+15 (once), diagonal skew ----
    {
        const int r  = t >> 5;         // 0..15
        const int cb = t & 31;         // 0..31
        const float4* src = (const float4*)(Whh + (size_t)(jt * 16 + r) * HID);
#pragma unroll
        for (int i = 0; i < 8; ++i) {
            int c4 = i * 32 + cb;                  // logical float4 col 0..255
            Wlds[r][(c4 + r) & 255] = src[c4];
        }
    }

    const int lane = t & 63;
    const int wv   = t >> 6;           // wave 0..7
    const int wb   = wv >> 1;          // batch quad 0..3
    const int wj   = wv & 1;           // j octet 0..1
    const int kc   = lane >> 3;        // k chunk 0..7
    const int jl   = lane & 7;         // j within octet
    const int rw   = wj * 8 + jl;      // W row within tile 0..15
    const int bb   = g * 16 + wb * 4;  // this wave's 4 batches
    const int j    = jt * 16 + rw;     // global j (meaningful for lane<8)

    __syncthreads();

    for (int s = 0; s < SEQ; ++s) {
        // ---- xw prefetch: barrier-independent, hide under the poll ----
        float xw0 = 0.f, xw1 = 0.f, xw2 = 0.f, xw3 = 0.f;
        if (lane < 8) {
            xw0 = out[((size_t)(bb + 0) * SEQ + s) * HID + j];
            xw1 = out[((size_t)(bb + 1) * SEQ + s) * HID + j];
            xw2 = out[((size_t)(bb + 2) * SEQ + s) * HID + j];
            xw3 = out[((size_t)(bb + 3) * SEQ + s) * HID + j];
        }

        float a0 = 0.f, a1 = 0.f, a2 = 0.f, a3 = 0.f;

        if (s > 0) {
            // ---- group barrier: all 64 j-tiles of group g finished s-1 ----
            if (t < 64) {
                const unsigned want = MAGIC + (unsigned)(s - 1);
                unsigned* f = flags + ((((s - 1) & 7) * 4 + g) * 64 + t);
                while (__hip_atomic_load(f, __ATOMIC_RELAXED, __HIP_MEMORY_SCOPE_AGENT) != want)
                    __builtin_amdgcn_s_sleep(1);
            }
            __syncthreads();
            __builtin_amdgcn_fence(__ATOMIC_ACQUIRE, "agent");

            const float4* h0 = (const float4*)(out + ((size_t)(bb + 0) * SEQ + (s - 1)) * HID);
            const float4* h1 = (const float4*)(out + ((size_t)(bb + 1) * SEQ + (s - 1)) * HID);
            const float4* h2 = (const float4*)(out + ((size_t)(bb + 2) * SEQ + (s - 1)) * HID);
            const float4* h3 = (const float4*)(out + ((size_t)(bb + 3) * SEQ + (s - 1)) * HID);

            const int base = kc * 32;          // this lane's 32-f4 k range

            float4 cur[4][4];                  // [i in chunk][batch]
#pragma unroll
            for (int i = 0; i < 4; ++i) {
                cur[i][0] = h0[base + i];
                cur[i][1] = h1[base + i];
                cur[i][2] = h2[base + i];
                cur[i][3] = h3[base + i];
            }

#pragma unroll
            for (int ch = 0; ch < 8; ++ch) {
                float4 nxt[4][4];
                if (ch < 7) {
                    const int nb = base + (ch + 1) * 4;
#pragma unroll
                    for (int i = 0; i < 4; ++i) {
                        nxt[i][0] = h0[nb + i];
                        nxt[i][1] = h1[nb + i];
                        nxt[i][2] = h2[nb + i];
                        nxt[i][3] = h3[nb + i];
                    }
                }
#pragma unroll
                for (int i = 0; i < 4; ++i) {
                    const int L = base + ch * 4 + i;
                    const float4 w4 = Wlds[rw][(L + rw) & 255];
                    const float4 x0 = cur[i][0];
                    const float4 x1 = cur[i][1];
                    const float4 x2 = cur[i][2];
                    const float4 x3 = cur[i][3];
                    a0 = fmaf(x0.x, w4.x, a0); a0 = fmaf(x0.y, w4.y, a0);
                    a0 = fmaf(x0.z, w4.z, a0); a0 = fmaf(x0.w, w4.w, a0);
                    a1 = fmaf(x1.x, w4.x, a1); a1 = fmaf(x1.y, w4.y, a1);
                    a1 = fmaf(x1.z, w4.z, a1); a1 = fmaf(x1.w, w4.w, a1);
                    a2 = fmaf(x2.x, w4.x, a2); a2 = fmaf(x2.y, w4.y, a2);
                    a2 = fmaf(x2.z, w4.z, a2); a2 = fmaf(x2.w, w4.w, a2);
                    a3 = fmaf(x3.x, w4.x, a3); a3 = fmaf(x3.y, w4.y, a3);
                    a3 = fmaf(x3.z, w4.z, a3); a3 = fmaf(x3.w, w4.w, a3);
                }
                if (ch < 7) {
#pragma unroll
                    for (int i = 0; i < 4; ++i) {
                        cur[i][0] = nxt[i][0];
                        cur[i][1] = nxt[i][1];
                        cur[i][2] = nxt[i][2];
                        cur[i][3] = nxt[i][3];
                    }
                }
            }
            // ---- reduce k-chunk partials (kc = lane bits [3:5]) ----
            a0 += __shfl_xor(a0, 8); a0 += __shfl_xor(a0, 16); a0 += __shfl_xor(a0, 32);
            a1 += __shfl_xor(a1, 8); a1 += __shfl_xor(a1, 16); a1 += __shfl_xor(a1, 32);
            a2 += __shfl_xor(a2, 8); a2 += __shfl_xor(a2, 16); a2 += __shfl_xor(a2, 32);
            a3 += __shfl_xor(a3, 8); a3 += __shfl_xor(a3, 16); a3 += __shfl_xor(a3, 32);
        }

        // ---- finalize: lanes 0..7 of each wave write 4 outputs ----
        if (lane < 8) {
            float* p0 = out + ((size_t)(bb + 0) * SEQ + s) * HID + j;
            float* p1 = out + ((size_t)(bb + 1) * SEQ + s) * HID + j;
            float* p2 = out + ((size_t)(bb + 2) * SEQ + s) * HID + j;
            float* p3 = out + ((size_t)(bb + 3) * SEQ + s) * HID + j;
            float v0 = tanhf(xw0 + a0);
            float v1 = tanhf(xw1 + a1);
            float v2 = tanhf(xw2 + a2);
            float v3 = tanhf(xw3 + a3);
            __hip_atomic_store(p0, v0, __ATOMIC_RELAXED, __HIP_MEMORY_SCOPE_AGENT);
            __hip_atomic_store(p1, v1, __ATOMIC_RELAXED, __HIP_MEMORY_SCOPE_AGENT);
            __hip_atomic_store(p2, v2, __ATOMIC_RELAXED, __HIP_MEMORY_SCOPE_AGENT);
            __hip_atomic_store(p3, v3, __ATOMIC_RELAXED, __HIP_MEMORY_SCOPE_AGENT);
        }
        __syncthreads();   // drains vmcnt(0): all block stores at coherence point
        if (t == 0)
            __hip_atomic_store(flags + (((s & 7) * 4 + g) * 64 + jt),
                               MAGIC + (unsigned)s,
                               __ATOMIC_RELAXED, __HIP_MEMORY_SCOPE_AGENT);
    }
}

// ============================================================================
extern "C" void kernel_launch(void* const* d_in, const int* in_sizes, int n_in,
                              void* d_out, int out_size, void* d_ws, size_t ws_size,
                              hipStream_t stream)
{
    (void)in_sizes; (void)n_in; (void)out_size; (void)ws_size;
    const float* x   = (const float*)d_in[0];   // (64,512,512)
    const float* Wih = (const float*)d_in[1];   // (1024,512)
    const float* Whh = (const float*)d_in[2];   // (1024,1024)
    const float* bih = (const float*)d_in[3];   // (1024,)
    const float* bhh = (const float*)d_in[4];   // (1024,)
    float* out = (float*)d_out;                 // (64,512,1024)
    unsigned* flags = (unsigned*)d_ws;          // 8 KB flag slots (poison-safe)

    dim3 g1(BATCH * SEQ / 128, HID / 128);      // (256, 8)
    xw_gemm<<<g1, 256, 0, stream>>>(x, Wih, bih, bhh, out);
    rnn_scan<<<256, 512, 0, stream>>>(Whh, out, flags);
}

// Round 3
// 10166.381 us; speedup vs baseline: 1.2089x; 1.2089x over previous
//
#include <hip/hip_runtime.h>

#define BATCH 64
#define SEQ   512
#define INP   512
#define HID   1024
#define MAGIC 0x13570000u

#define NG 8      // batch groups
#define GB 8      // batches per group
#define NJT 64    // j tiles
#define TJ 16     // j per tile

// ============================================================================
// Phase 1: out[m][n] = sum_f X[m][f] * Wih[n][f] + bih[n] + bhh[n]
// Classic fp32 SGEMM: 128x128 tile, BK=8, 256 threads, 8x8 micro. ~130 us.
// ============================================================================
__global__ __launch_bounds__(256) void xw_gemm(
    const float* __restrict__ X, const float* __restrict__ Wih,
    const float* __restrict__ bih, const float* __restrict__ bhh,
    float* __restrict__ out)
{
    __shared__ float As[8][128];
    __shared__ float Bs[8][128];
    const int t  = threadIdx.x;
    const int m0 = blockIdx.x * 128;
    const int n0 = blockIdx.y * 128;
    const int lr = t >> 1;
    const int lk = (t & 1) * 4;
    const int ty = t >> 4;
    const int tx = t & 15;

    float acc[8][8];
#pragma unroll
    for (int i = 0; i < 8; ++i)
#pragma unroll
        for (int j = 0; j < 8; ++j) acc[i][j] = 0.f;

    const float* xrow = X   + (size_t)(m0 + lr) * INP + lk;
    const float* wrow = Wih + (size_t)(n0 + lr) * INP + lk;

    for (int k0 = 0; k0 < INP; k0 += 8) {
        float4 av = *(const float4*)(xrow + k0);
        float4 bv = *(const float4*)(wrow + k0);
        __syncthreads();
        As[lk + 0][lr] = av.x; As[lk + 1][lr] = av.y;
        As[lk + 2][lr] = av.z; As[lk + 3][lr] = av.w;
        Bs[lk + 0][lr] = bv.x; Bs[lk + 1][lr] = bv.y;
        Bs[lk + 2][lr] = bv.z; Bs[lk + 3][lr] = bv.w;
        __syncthreads();
#pragma unroll
        for (int kk = 0; kk < 8; ++kk) {
            float4 a0 = *(const float4*)&As[kk][ty * 4];
            float4 a1 = *(const float4*)&As[kk][64 + ty * 4];
            float4 b0 = *(const float4*)&Bs[kk][tx * 4];
            float4 b1 = *(const float4*)&Bs[kk][64 + tx * 4];
            float am[8] = {a0.x, a0.y, a0.z, a0.w, a1.x, a1.y, a1.z, a1.w};
            float bn[8] = {b0.x, b0.y, b0.z, b0.w, b1.x, b1.y, b1.z, b1.w};
#pragma unroll
            for (int i = 0; i < 8; ++i)
#pragma unroll
                for (int j = 0; j < 8; ++j)
                    acc[i][j] = fmaf(am[i], bn[j], acc[i][j]);
        }
    }

    const int nA = n0 + tx * 4;
    const int nB = n0 + 64 + tx * 4;
    float4 bA1 = *(const float4*)(bih + nA);
    float4 bA2 = *(const float4*)(bhh + nA);
    float4 bB1 = *(const float4*)(bih + nB);
    float4 bB2 = *(const float4*)(bhh + nB);
    float4 biasA = make_float4(bA1.x + bA2.x, bA1.y + bA2.y, bA1.z + bA2.z, bA1.w + bA2.w);
    float4 biasB = make_float4(bB1.x + bB2.x, bB1.y + bB2.y, bB1.z + bB2.z, bB1.w + bB2.w);

#pragma unroll
    for (int i = 0; i < 8; ++i) {
        int mloc = (i < 4) ? (ty * 4 + i) : (64 + ty * 4 + (i - 4));
        size_t m = (size_t)(m0 + mloc);
        float4 vA = make_float4(acc[i][0] + biasA.x, acc[i][1] + biasA.y,
                                acc[i][2] + biasA.z, acc[i][3] + biasA.w);
        float4 vB = make_float4(acc[i][4] + biasB.x, acc[i][5] + biasB.y,
                                acc[i][6] + biasB.z, acc[i][7] + biasB.w);
        *(float4*)(out + m * HID + nA) = vA;
        *(float4*)(out + m * HID + nB) = vB;
    }
}

// ============================================================================
// Phase 2 (R3): persistent scan, K-split waves, register-resident W,
// coalesced h staging via LDS, 2 blocks/CU for sync-latency hiding.
//
// Grid 512 = 8 groups (8 batches) x 64 j-tiles (16 j). Block: 256 thr, 4 waves.
// Wave w owns k-range [w*256, w*256+256). Lane (kc2=bits[4:5], jl=bits[0:3])
// owns k-f4 cols base4=w*64+kc2*16 .. +16 and output column j=jt*16+jl.
// W fragment: 16 float4 in VGPRs, loaded once (rot-ordered so the LDS h-read
// addresses per instr land 2 per bank quad = free per m136).
// Per step: poll group flags -> coalesced stage h[s-1] rows into LDS (32 b128
// loads) -> 512 fma/lane from LDS broadcast -> shfl kc2-reduce -> LDS
// cross-wave reduce -> tanh -> agent store -> flag.
// ============================================================================
__global__ __launch_bounds__(256, 2) void rnn_scan(
    const float* __restrict__ Whh, float* __restrict__ out,
    unsigned* __restrict__ flags)
{
    __shared__ float4 Hlds[GB][256];      // 32 KB: h[s-1] rows for this group
    __shared__ float  Pbuf[4][GB][TJ];    // 2 KB: per-wave j-partials

    const int t    = threadIdx.x;
    const int g    = blockIdx.x >> 6;     // batch group 0..7
    const int jt   = blockIdx.x & 63;     // j tile 0..63
    const int lane = t & 63;
    const int w    = t >> 6;              // wave = k-quarter 0..3
    const int kc2  = (lane >> 4) & 3;     // k sub-chunk 0..3 (16 f4 each)
    const int jl   = lane & 15;           // output j within tile
    const int base4 = w * 64 + kc2 * 16;  // this lane's first k f4-col

    // ---- W fragment in registers (one-time). Wreg[q*4+r] pairs with the
    // rotated LDS read Hlds[b][base4 + 4*((kc2+q)&3) + r]. ----
    float4 Wreg[16];
    {
        const float4* wr = (const float4*)(Whh + (size_t)(jt * TJ + jl) * HID) + base4;
#pragma unroll
        for (int q = 0; q < 4; ++q) {
            const int rot = 4 * ((kc2 + q) & 3);
#pragma unroll
            for (int r = 0; r < 4; ++r)
                Wreg[q * 4 + r] = wr[rot + r];
        }
    }

    const int bo = t >> 4;                // t<128: batch 0..7
    const int jo = t & 15;                // t<128: j within tile

    for (int s = 0; s < SEQ; ++s) {
        // ---- xw prefetch (barrier-independent; hides under the poll) ----
        float xw = 0.f;
        if (t < 128)
            xw = out[((size_t)(g * GB + bo) * SEQ + s) * HID + jt * TJ + jo];

        float p[GB];
#pragma unroll
        for (int b = 0; b < GB; ++b) p[b] = 0.f;

        if (s > 0) {
            // ---- group barrier: all 64 j-tiles of group g finished s-1 ----
            if (t < 64) {
                const unsigned want = MAGIC + (unsigned)(s - 1);
                unsigned* f = flags + ((((s - 1) & 3) * NG + g) * 64 + t);
                while (__hip_atomic_load(f, __ATOMIC_RELAXED, __HIP_MEMORY_SCOPE_AGENT) != want)
                    __builtin_amdgcn_s_sleep(1);
            }
            __syncthreads();
            __builtin_amdgcn_fence(__ATOMIC_ACQUIRE, "agent");

            // ---- coalesced stage: wave w loads batch rows w*2, w*2+1 ----
#pragma unroll
            for (int rr = 0; rr < 2; ++rr) {
                const int b = w * 2 + rr;
                const float4* hrow =
                    (const float4*)(out + ((size_t)(g * GB + b) * SEQ + (s - 1)) * HID);
#pragma unroll
                for (int i2 = 0; i2 < 4; ++i2)
                    Hlds[b][i2 * 64 + lane] = hrow[i2 * 64 + lane];
            }
            __syncthreads();

            // ---- compute: 16 k-f4 x 8 batches, W from regs, h broadcast ----
#pragma unroll
            for (int q = 0; q < 4; ++q) {
                const int rot = 4 * ((kc2 + q) & 3);
#pragma unroll
                for (int r = 0; r < 4; ++r) {
                    const float4 wv = Wreg[q * 4 + r];
#pragma unroll
                    for (int b = 0; b < GB; ++b) {
                        const float4 h4 = Hlds[b][base4 + rot + r];
                        p[b] = fmaf(wv.x, h4.x, p[b]);
                        p[b] = fmaf(wv.y, h4.y, p[b]);
                        p[b] = fmaf(wv.z, h4.z, p[b]);
                        p[b] = fmaf(wv.w, h4.w, p[b]);
                    }
                }
            }
            // ---- reduce over kc2 (lane bits 4,5) ----
#pragma unroll
            for (int b = 0; b < GB; ++b) {
                p[b] += __shfl_xor(p[b], 16);
                p[b] += __shfl_xor(p[b], 32);
            }
        }

        // ---- cross-wave reduction via LDS (zeros at s==0) ----
        if (lane < 16) {
#pragma unroll
            for (int b = 0; b < GB; ++b) Pbuf[w][b][jl] = p[b];
        }
        __syncthreads();

        if (t < 128) {
            float tot = xw + Pbuf[0][bo][jo] + Pbuf[1][bo][jo]
                           + Pbuf[2][bo][jo] + Pbuf[3][bo][jo];
            float v = tanhf(tot);
            __hip_atomic_store(
                out + ((size_t)(g * GB + bo) * SEQ + s) * HID + jt * TJ + jo,
                v, __ATOMIC_RELAXED, __HIP_MEMORY_SCOPE_AGENT);
        }
        __syncthreads();   // drains vmcnt(0): stores at coherence point
        if (t == 0)
            __hip_atomic_store(flags + (((s & 3) * NG + g) * 64 + jt),
                               MAGIC + (unsigned)s,
                               __ATOMIC_RELAXED, __HIP_MEMORY_SCOPE_AGENT);
    }
}

// ============================================================================
extern "C" void kernel_launch(void* const* d_in, const int* in_sizes, int n_in,
                              void* d_out, int out_size, void* d_ws, size_t ws_size,
                              hipStream_t stream)
{
    (void)in_sizes; (void)n_in; (void)out_size; (void)ws_size;
    const float* x   = (const float*)d_in[0];   // (64,512,512)
    const float* Wih = (const float*)d_in[1];   // (1024,512)
    const float* Whh = (const float*)d_in[2];   // (1024,1024)
    const float* bih = (const float*)d_in[3];   // (1024,)
    const float* bhh = (const float*)d_in[4];   // (1024,)
    float* out = (float*)d_out;                 // (64,512,1024)
    unsigned* flags = (unsigned*)d_ws;          // 8 KB flag slots (poison-safe)

    dim3 g1(BATCH * SEQ / 128, HID / 128);      // (256, 8)
    xw_gemm<<<g1, 256, 0, stream>>>(x, Wih, bih, bhh, out);
    rnn_scan<<<NG * NJT, 256, 0, stream>>>(Whh, out, flags);
}